// Round 9
// baseline (751.268 us; speedup 1.0000x reference)
//
#include <hip/hip_runtime.h>
#include <hip/hip_bf16.h>

typedef __attribute__((ext_vector_type(8))) short bf16x8;
typedef __attribute__((ext_vector_type(4))) float f32x4;

#define MFMA(a,b,c) __builtin_amdgcn_mfma_f32_16x16x32_bf16((a),(b),(c),0,0,0)

// ---- workspace (bf16) element offsets ----
#define WS_W1T 0
#define WS_W2T 229376
#define WS_G1T 458752
#define WS_TGP 655360
#define WS_FGT 679936
#define WS_TOTAL 704512

__device__ __forceinline__ ushort f2b(float f) {
  __hip_bfloat16 h = __float2bfloat16(f);
  ushort u; __builtin_memcpy(&u, &h, 2); return u;
}
__device__ __forceinline__ float silu_f(float x) { return x / (1.f + __expf(-x)); }
__device__ __forceinline__ bf16x8 ld8(const ushort* p) {
  return *reinterpret_cast<const bf16x8*>(p);
}
__device__ __forceinline__ ushort4 pk4(float a, float b, float c, float d) {
  return make_ushort4(f2b(a), f2b(b), f2b(c), f2b(d));
}
// XOR-swizzled addressing: 512B-row buffers (G) and 256B-row buffers (GT).
// slot16 ^= (row&7) -> uniform 8-lane spread over the 8 bank-quads (T2/G4).
__device__ __forceinline__ ushort* swzG(ushort* base, int row, int colByte) {
  return (ushort*)((char*)base + row * 512 + (((colByte >> 4) ^ (row & 7)) << 4) + (colByte & 15));
}
__device__ __forceinline__ ushort* swzT(ushort* base, int row, int colByte) {
  return (ushort*)((char*)base + row * 256 + (((colByte >> 4) ^ (row & 7)) << 4) + (colByte & 15));
}

__global__ void prep_kernel(const float* __restrict__ w1, const float* __restrict__ w2,
                            const float* __restrict__ g1, const float* __restrict__ g2,
                            const float* __restrict__ g3, const float* __restrict__ tg,
                            const float* __restrict__ fg, ushort* __restrict__ o) {
  int idx = blockIdx.x * blockDim.x + threadIdx.x;
  if (idx >= WS_TOTAL) return;
  float v;
  if (idx < WS_W2T) {                        // w1T[l][h][c] = w1[l][c][h]
    int l = idx >> 15, rem = idx & 32767, h = rem >> 7, c = rem & 127;
    v = w1[(l << 15) + c * 256 + h];
  } else if (idx < WS_G1T) {                 // w2T[l][o][h] = w2[l][h][o]
    int j = idx - WS_W2T;
    int l = j >> 15, rem = j & 32767, oo = rem >> 8, h = rem & 255;
    v = w2[(l << 15) + h * 128 + oo];
  } else if (idx < WS_TGP) {                 // gT[n][k] = g[k][n]
    int j = idx - WS_G1T;
    int m = j >> 16, r = j & 65535, n2 = r >> 8, k = r & 255;
    const float* g = (m == 0) ? g1 : ((m == 1) ? g2 : g3);
    v = g[k * 256 + n2];
  } else if (idx < WS_FGT) {                 // tgP[r][i]
    int j = idx - WS_TGP, r = j >> 6, i2 = j & 63;
    v = (r < 324 && i2 < 49) ? tg[r * 49 + i2] : 0.f;
  } else {                                   // fgT[i][r]
    int j = idx - WS_FGT, i2 = j / 384, r = j % 384;
    v = (i2 < 49 && r < 324) ? fg[r * 49 + i2] : 0.f;
  }
  o[idx] = f2b(v);
}

// One block per node. 8 waves N-split (wave wv owns 32 h-cols). M=128 grid rows
// per iteration, 3 iters. Ping-pong: TG->Ga, G1:Ga->Gb, G2:Gb->Ga,
// G3:Ga->GT(in Gb), FG reads Gb. 4 barriers/iter. All G/GT/xo accesses swizzled.
__global__ __launch_bounds__(512, 1) void ffn_main(
    const float* __restrict__ nf, const float* __restrict__ b1,
    const float* __restrict__ b2, const float* __restrict__ wsg,
    const float* __restrict__ bs, const ushort* __restrict__ wbf,
    float* __restrict__ out)
{
  // 131,072 B LDS: Ga [128][256] swz + Gb [128][256] swz (doubles as GT [256][128] swz)
  __shared__ __align__(16) ushort sm[65536];
  ushort* Ga = sm;
  ushort* Gb = sm + 32768;
  ushort* s_nf  = Ga;           // [52][136] prologue alias
  ushort* s_xbT = Gb;           // [256][72] x^T alias (dead once xbf loaded)
  ushort* s_xo  = Ga;           // [64][256] swz epilogue alias

  const int tid  = threadIdx.x;
  const int lane = tid & 63;
  const int wv   = tid >> 6;    // 0..7 (N slice)
  const int lr   = lane & 15;
  const int lk   = lane >> 4;   // 0..3

  const float* nfp = nf + (size_t)blockIdx.x * 6272;

  // ---------------- prologue: zero x^T area, stage node_feats (bf16), gating ----------------
  float gat = 0.f;
  {
    uint4 z = {0,0,0,0};
    for (int idx = tid; idx < 2304; idx += 512)         // 18432 ushorts
      *reinterpret_cast<uint4*>(&s_xbT[idx * 8]) = z;
    for (int idx = tid; idx < 52 * 32; idx += 512) {
      int r = idx >> 5, c4 = (idx & 31) << 2;
      float4 v = (r < 49) ? *reinterpret_cast<const float4*>(nfp + (r << 7) + c4)
                          : make_float4(0.f, 0.f, 0.f, 0.f);
      *reinterpret_cast<ushort4*>(&s_nf[r * 136 + c4]) = pk4(v.x, v.y, v.z, v.w);
    }
    if (tid < 256) {
      float a = bs[tid];
      #pragma unroll 4
      for (int c = 0; c < 128; ++c) a = fmaf(nfp[c], wsg[(c << 8) + tid], a);
      gat = silu_f(a);
    }
  }
  __syncthreads();

  // ---------------- SO3 linear 1: x^T[h][i] into s_xbT ----------------
  {
    const ushort* w1T = wbf + WS_W1T;
    #pragma unroll 1
    for (int l = 0; l < 7; ++l) {
      f32x4 a0 = {0.f,0.f,0.f,0.f}, a1 = {0.f,0.f,0.f,0.f};
      const int arow = l * l + lr;                    // <= 51, rows 49..51 zeroed
      const ushort* bb = w1T + (l << 15);
      #pragma unroll
      for (int ks = 0; ks < 4; ++ks) {
        bf16x8 af  = ld8(&s_nf[arow * 136 + ks * 32 + lk * 8]);
        bf16x8 bf0 = ld8(bb + ((wv * 32 + lr) << 7) + ks * 32 + lk * 8);
        bf16x8 bf1 = ld8(bb + ((wv * 32 + 16 + lr) << 7) + ks * 32 + lk * 8);
        a0 = MFMA(af, bf0, a0);
        a1 = MFMA(af, bf1, a1);
      }
      const int nv = 2 * l + 1;
      #pragma unroll
      for (int reg = 0; reg < 4; ++reg) {
        int il = lk * 4 + reg;
        if (il < nv) {
          int ig = l * l + il;
          int h0 = wv * 32 + lr, h1 = h0 + 16;
          s_xbT[h0 * 72 + ig] = f2b(a0[reg] + (ig == 0 ? b1[h0] : 0.f));
          s_xbT[h1 * 72 + ig] = f2b(a1[reg] + (ig == 0 ? b1[h1] : 0.f));
        }
      }
    }
  }
  __syncthreads();

  // to_grid B: x^T col-slice, persistent regs (s_xbT region is overwritten by G1)
  bf16x8 xbf[2][2];
  #pragma unroll
  for (int nt = 0; nt < 2; ++nt)
    #pragma unroll
    for (int ks = 0; ks < 2; ++ks)
      xbf[nt][ks] = ld8(&s_xbT[(wv * 32 + nt * 16 + lr) * 72 + ks * 32 + lk * 8]);

  f32x4 xo[4][2];
  #pragma unroll
  for (int mt = 0; mt < 4; ++mt)
    #pragma unroll
    for (int nt = 0; nt < 2; ++nt) xo[mt][nt] = (f32x4){0.f,0.f,0.f,0.f};

  const ushort* tgP = wbf + WS_TGP;
  const ushort* fgT = wbf + WS_FGT;

  #pragma unroll 1
  for (int ch = 0; ch < 3; ++ch) {           // 128 grid rows per iteration
    // ---- TG: Ga = tg[128,64p] @ x[64p,256]. reg-dim -> h. ----
    {
      f32x4 c[8][2];
      #pragma unroll
      for (int mt = 0; mt < 8; ++mt)
        #pragma unroll
        for (int nt = 0; nt < 2; ++nt) c[mt][nt] = (f32x4){0.f,0.f,0.f,0.f};
      #pragma unroll
      for (int ks = 0; ks < 2; ++ks) {
        bf16x8 atg[8];
        #pragma unroll
        for (int mt = 0; mt < 8; ++mt)
          atg[mt] = ld8(tgP + ((ch * 128 + mt * 16 + lr) << 6) + ks * 32 + lk * 8);
        #pragma unroll
        for (int mt = 0; mt < 8; ++mt)
          #pragma unroll
          for (int nt = 0; nt < 2; ++nt) c[mt][nt] = MFMA(xbf[nt][ks], atg[mt], c[mt][nt]);
      }
      #pragma unroll
      for (int mt = 0; mt < 8; ++mt)
        #pragma unroll
        for (int nt = 0; nt < 2; ++nt)
          *reinterpret_cast<ushort4*>(swzG(Ga, mt * 16 + lr, wv * 64 + nt * 32 + lk * 8)) =
              pk4(c[mt][nt][0], c[mt][nt][1], c[mt][nt][2], c[mt][nt][3]);
    }
    __syncthreads();

    // ---- G1: Gb = silu(Ga @ g1). reg-dim -> h. ----
    {
      const ushort* gT = wbf + WS_G1T;
      f32x4 c[8][2];
      #pragma unroll
      for (int mt = 0; mt < 8; ++mt)
        #pragma unroll
        for (int nt = 0; nt < 2; ++nt) c[mt][nt] = (f32x4){0.f,0.f,0.f,0.f};
      #pragma unroll
      for (int ks = 0; ks < 8; ++ks) {
        bf16x8 bstr[2];
        #pragma unroll
        for (int nt = 0; nt < 2; ++nt)
          bstr[nt] = ld8(gT + ((wv * 32 + nt * 16 + lr) << 8) + ks * 32 + lk * 8);
        bf16x8 af[8];
        #pragma unroll
        for (int mt = 0; mt < 8; ++mt)
          af[mt] = ld8(swzG(Ga, mt * 16 + lr, ks * 64 + lk * 16));
        #pragma unroll
        for (int mt = 0; mt < 8; ++mt)
          #pragma unroll
          for (int nt = 0; nt < 2; ++nt) c[mt][nt] = MFMA(bstr[nt], af[mt], c[mt][nt]);
      }
      #pragma unroll
      for (int mt = 0; mt < 8; ++mt)
        #pragma unroll
        for (int nt = 0; nt < 2; ++nt)
          *reinterpret_cast<ushort4*>(swzG(Gb, mt * 16 + lr, wv * 64 + nt * 32 + lk * 8)) =
              pk4(silu_f(c[mt][nt][0]), silu_f(c[mt][nt][1]),
                  silu_f(c[mt][nt][2]), silu_f(c[mt][nt][3]));
    }
    __syncthreads();

    // ---- G2: Ga = silu(Gb @ g2). ----
    {
      const ushort* gT = wbf + WS_G1T + 65536;
      f32x4 c[8][2];
      #pragma unroll
      for (int mt = 0; mt < 8; ++mt)
        #pragma unroll
        for (int nt = 0; nt < 2; ++nt) c[mt][nt] = (f32x4){0.f,0.f,0.f,0.f};
      #pragma unroll
      for (int ks = 0; ks < 8; ++ks) {
        bf16x8 bstr[2];
        #pragma unroll
        for (int nt = 0; nt < 2; ++nt)
          bstr[nt] = ld8(gT + ((wv * 32 + nt * 16 + lr) << 8) + ks * 32 + lk * 8);
        bf16x8 af[8];
        #pragma unroll
        for (int mt = 0; mt < 8; ++mt)
          af[mt] = ld8(swzG(Gb, mt * 16 + lr, ks * 64 + lk * 16));
        #pragma unroll
        for (int mt = 0; mt < 8; ++mt)
          #pragma unroll
          for (int nt = 0; nt < 2; ++nt) c[mt][nt] = MFMA(bstr[nt], af[mt], c[mt][nt]);
      }
      #pragma unroll
      for (int mt = 0; mt < 8; ++mt)
        #pragma unroll
        for (int nt = 0; nt < 2; ++nt)
          *reinterpret_cast<ushort4*>(swzG(Ga, mt * 16 + lr, wv * 64 + nt * 32 + lk * 8)) =
              pk4(silu_f(c[mt][nt][0]), silu_f(c[mt][nt][1]),
                  silu_f(c[mt][nt][2]), silu_f(c[mt][nt][3]));
    }
    __syncthreads();

    // ---- G3: GT(in Gb) = (Ga @ g3)^T. reg-dim -> r. ----
    {
      const ushort* gT = wbf + WS_G1T + 131072;
      f32x4 c[8][2];
      #pragma unroll
      for (int mt = 0; mt < 8; ++mt)
        #pragma unroll
        for (int nt = 0; nt < 2; ++nt) c[mt][nt] = (f32x4){0.f,0.f,0.f,0.f};
      #pragma unroll
      for (int ks = 0; ks < 8; ++ks) {
        bf16x8 bstr[2];
        #pragma unroll
        for (int nt = 0; nt < 2; ++nt)
          bstr[nt] = ld8(gT + ((wv * 32 + nt * 16 + lr) << 8) + ks * 32 + lk * 8);
        bf16x8 af[8];
        #pragma unroll
        for (int mt = 0; mt < 8; ++mt)
          af[mt] = ld8(swzG(Ga, mt * 16 + lr, ks * 64 + lk * 16));
        #pragma unroll
        for (int mt = 0; mt < 8; ++mt)
          #pragma unroll
          for (int nt = 0; nt < 2; ++nt) c[mt][nt] = MFMA(af[mt], bstr[nt], c[mt][nt]);
      }
      __syncthreads();   // Ga reads done AND Gb(G2-source) fully consumed earlier; GT writes next
      #pragma unroll
      for (int mt = 0; mt < 8; ++mt)
        #pragma unroll
        for (int nt = 0; nt < 2; ++nt) {
          int h = wv * 32 + nt * 16 + lr;
          *reinterpret_cast<ushort4*>(swzT(Gb, h, mt * 32 + lk * 8)) =
              pk4(c[mt][nt][0], c[mt][nt][1], c[mt][nt][2], c[mt][nt][3]);
        }
    }
    __syncthreads();

    // ---- FG: xo += fg[128]^T @ GT. reg-dim -> h. No trailing barrier
    //      (next TG writes Ga only; its barrier orders Gb reuse). ----
    {
      #pragma unroll
      for (int ks = 0; ks < 4; ++ks) {
        bf16x8 afg[4];
        #pragma unroll
        for (int mt = 0; mt < 4; ++mt)
          afg[mt] = ld8(fgT + (mt * 16 + lr) * 384 + ch * 128 + ks * 32 + lk * 8);
        bf16x8 bfr[2];
        #pragma unroll
        for (int nt = 0; nt < 2; ++nt)
          bfr[nt] = ld8(swzT(Gb, wv * 32 + nt * 16 + lr, ks * 64 + lk * 16));
        #pragma unroll
        for (int mt = 0; mt < 4; ++mt)
          #pragma unroll
          for (int nt = 0; nt < 2; ++nt) xo[mt][nt] = MFMA(bfr[nt], afg[mt], xo[mt][nt]);
      }
    }
  }

  // ---------------- epilogue: xo -> s_xo (swz Ga, free after G3 bar), gating, SO3L2 ----------------
  #pragma unroll
  for (int mt = 0; mt < 4; ++mt)
    #pragma unroll
    for (int nt = 0; nt < 2; ++nt)
      *reinterpret_cast<ushort4*>(swzG(Ga, mt * 16 + lr, wv * 64 + nt * 32 + lk * 8)) =
          pk4(xo[mt][nt][0], xo[mt][nt][1], xo[mt][nt][2], xo[mt][nt][3]);
  __syncthreads();
  if (tid < 256) s_xo[tid] = f2b(gat);   // row 0 (swizzle-identity) <- gating
  __syncthreads();

  {
    const ushort* w2T = wbf + WS_W2T;
    float* outp = out + (size_t)blockIdx.x * 6272;
    const float4 bb2 = *reinterpret_cast<const float4*>(b2 + wv * 16 + lk * 4);
    #pragma unroll 1
    for (int l = 0; l < 7; ++l) {
      f32x4 acc = {0.f,0.f,0.f,0.f};
      const ushort* bb = w2T + (l << 15);
      const int arow = l * l + lr;                 // <= 51; rows 49..63 are zeros
      #pragma unroll
      for (int ks = 0; ks < 8; ++ks) {
        bf16x8 xf = ld8(swzG(Ga, arow, ks * 64 + lk * 16));
        bf16x8 wf = ld8(bb + ((wv * 16 + lr) << 8) + ks * 32 + lk * 8);
        acc = MFMA(wf, xf, acc);                   // reg-dim -> o
      }
      if (lr < 2 * l + 1) {
        int ig = l * l + lr;
        float4 v = make_float4(acc[0], acc[1], acc[2], acc[3]);
        if (ig == 0) { v.x += bb2.x; v.y += bb2.y; v.z += bb2.z; v.w += bb2.w; }
        *reinterpret_cast<float4*>(outp + (ig << 7) + wv * 16 + lk * 4) = v;
      }
    }
  }
}

extern "C" void kernel_launch(void* const* d_in, const int* in_sizes, int n_in,
                              void* d_out, int out_size, void* d_ws, size_t ws_size,
                              hipStream_t stream) {
  const float* nf  = (const float*)d_in[0];
  const float* w1  = (const float*)d_in[1];
  const float* b1  = (const float*)d_in[2];
  const float* w2  = (const float*)d_in[3];
  const float* b2  = (const float*)d_in[4];
  const float* wsg = (const float*)d_in[5];
  const float* bs  = (const float*)d_in[6];
  const float* g1  = (const float*)d_in[7];
  const float* g2  = (const float*)d_in[8];
  const float* g3  = (const float*)d_in[9];
  const float* tg  = (const float*)d_in[10];
  const float* fg  = (const float*)d_in[11];
  ushort* wbf = (ushort*)d_ws;
  float* out = (float*)d_out;

  prep_kernel<<<(WS_TOTAL + 255) / 256, 256, 0, stream>>>(w1, w2, g1, g2, g3, tg, fg, wbf);
  ffn_main<<<1024, 512, 0, stream>>>(nf, b1, b2, wsg, bs, wbf, out);
}

// Round 10
// 666.901 us; speedup vs baseline: 1.1265x; 1.1265x over previous
//
#include <hip/hip_runtime.h>
#include <hip/hip_bf16.h>

typedef __attribute__((ext_vector_type(8))) short bf16x8;
typedef __attribute__((ext_vector_type(4))) float f32x4;

#define MFMA(a,b,c) __builtin_amdgcn_mfma_f32_16x16x32_bf16((a),(b),(c),0,0,0)

// ---- workspace (bf16) element offsets ----
#define WS_W1T 0
#define WS_W2T 229376
#define WS_G1T 458752
#define WS_TGP 655360
#define WS_FGT 679936
#define WS_TOTAL 704512

__device__ __forceinline__ ushort f2b(float f) {
  __hip_bfloat16 h = __float2bfloat16(f);
  ushort u; __builtin_memcpy(&u, &h, 2); return u;
}
__device__ __forceinline__ float silu_f(float x) { return x / (1.f + __expf(-x)); }
__device__ __forceinline__ bf16x8 ld8(const ushort* p) {
  return *reinterpret_cast<const bf16x8*>(p);
}
__device__ __forceinline__ ushort4 pk4(float a, float b, float c, float d) {
  return make_ushort4(f2b(a), f2b(b), f2b(c), f2b(d));
}

__global__ void prep_kernel(const float* __restrict__ w1, const float* __restrict__ w2,
                            const float* __restrict__ g1, const float* __restrict__ g2,
                            const float* __restrict__ g3, const float* __restrict__ tg,
                            const float* __restrict__ fg, ushort* __restrict__ o) {
  int idx = blockIdx.x * blockDim.x + threadIdx.x;
  if (idx >= WS_TOTAL) return;
  float v;
  if (idx < WS_W2T) {                        // w1T[l][h][c] = w1[l][c][h]
    int l = idx >> 15, rem = idx & 32767, h = rem >> 7, c = rem & 127;
    v = w1[(l << 15) + c * 256 + h];
  } else if (idx < WS_G1T) {                 // w2T[l][o][h] = w2[l][h][o]
    int j = idx - WS_W2T;
    int l = j >> 15, rem = j & 32767, oo = rem >> 8, h = rem & 255;
    v = w2[(l << 15) + h * 128 + oo];
  } else if (idx < WS_TGP) {                 // gT[n][k] = g[k][n]
    int j = idx - WS_G1T;
    int m = j >> 16, r = j & 65535, n2 = r >> 8, k = r & 255;
    const float* g = (m == 0) ? g1 : ((m == 1) ? g2 : g3);
    v = g[k * 256 + n2];
  } else if (idx < WS_TGP + 24576 && idx >= WS_TGP) {  // tgP[r][i]
    int j = idx - WS_TGP, r = j >> 6, i2 = j & 63;
    v = (r < 324 && i2 < 49) ? tg[r * 49 + i2] : 0.f;
  } else {                                   // fgT[i][r]
    int j = idx - WS_FGT, i2 = j / 384, r = j % 384;
    v = (i2 < 49 && r < 324) ? fg[r * 49 + i2] : 0.f;
  }
  o[idx] = f2b(v);
}

// One block per node. 8 waves N-split (wave wv owns 32 h-cols). M=128 grid rows
// per iteration, 3 iters. PING-PONG (no in-place): TG->Ga |b| G1:Ga->Gb |b|
// G2:Gb->Ga |b| G3:Ga->GT(Gb) |b| FG:Gb  == 4 barriers/iter (round 8 had 7).
// Plain padded strides (264/136) — NO runtime swizzle (round-9 lesson: XOR
// swizzle defeats immediate-offset folding -> address-reg explosion -> 1GB spill).
// A-fragments processed in halves of 4 to cap arch-VGPR live ranges.
__global__ __launch_bounds__(512, 1) void ffn_main(
    const float* __restrict__ nf, const float* __restrict__ b1,
    const float* __restrict__ b2, const float* __restrict__ wsg,
    const float* __restrict__ bs, const ushort* __restrict__ wbf,
    float* __restrict__ out)
{
  // LDS: Ga [128][264] (33792 ush) + Gb max([128][264], GT [256][136]) (34816 ush)
  //    = 68608 ush = 137,216 B
  __shared__ __align__(16) ushort sm[68608];
  ushort* Ga = sm;
  ushort* Gb = sm + 33792;
  ushort* s_nf  = Ga;           // [52][136] prologue alias
  ushort* s_xbT = Gb;           // [256][72] x^T alias (dead once xbf loaded)
  ushort* s_xo  = Ga;           // [64][264] epilogue alias

  const int tid  = threadIdx.x;
  const int lane = tid & 63;
  const int wv   = tid >> 6;    // 0..7 (N slice)
  const int lr   = lane & 15;
  const int lk   = lane >> 4;   // 0..3

  const float* nfp = nf + (size_t)blockIdx.x * 6272;

  // ---------------- prologue: zero x^T area, stage node_feats (bf16), gating ----------------
  float gat = 0.f;
  {
    uint4 z = {0,0,0,0};
    for (int idx = tid; idx < 2304; idx += 512)         // 18432 ushorts
      *reinterpret_cast<uint4*>(&s_xbT[idx * 8]) = z;
    for (int idx = tid; idx < 52 * 32; idx += 512) {
      int r = idx >> 5, c4 = (idx & 31) << 2;
      float4 v = (r < 49) ? *reinterpret_cast<const float4*>(nfp + (r << 7) + c4)
                          : make_float4(0.f, 0.f, 0.f, 0.f);
      *reinterpret_cast<ushort4*>(&s_nf[r * 136 + c4]) = pk4(v.x, v.y, v.z, v.w);
    }
    if (tid < 256) {
      float a = bs[tid];
      #pragma unroll 4
      for (int c = 0; c < 128; ++c) a = fmaf(nfp[c], wsg[(c << 8) + tid], a);
      gat = silu_f(a);
    }
  }
  __syncthreads();

  // ---------------- SO3 linear 1: x^T[h][i] into s_xbT ----------------
  {
    const ushort* w1T = wbf + WS_W1T;
    #pragma unroll 1
    for (int l = 0; l < 7; ++l) {
      f32x4 a0 = {0.f,0.f,0.f,0.f}, a1 = {0.f,0.f,0.f,0.f};
      const int arow = l * l + lr;                    // <= 51, rows 49..51 zeroed
      const ushort* bb = w1T + (l << 15);
      #pragma unroll
      for (int ks = 0; ks < 4; ++ks) {
        bf16x8 af  = ld8(&s_nf[arow * 136 + ks * 32 + lk * 8]);
        bf16x8 bf0 = ld8(bb + ((wv * 32 + lr) << 7) + ks * 32 + lk * 8);
        bf16x8 bf1 = ld8(bb + ((wv * 32 + 16 + lr) << 7) + ks * 32 + lk * 8);
        a0 = MFMA(af, bf0, a0);
        a1 = MFMA(af, bf1, a1);
      }
      const int nv = 2 * l + 1;
      #pragma unroll
      for (int reg = 0; reg < 4; ++reg) {
        int il = lk * 4 + reg;
        if (il < nv) {
          int ig = l * l + il;
          int h0 = wv * 32 + lr, h1 = h0 + 16;
          s_xbT[h0 * 72 + ig] = f2b(a0[reg] + (ig == 0 ? b1[h0] : 0.f));
          s_xbT[h1 * 72 + ig] = f2b(a1[reg] + (ig == 0 ? b1[h1] : 0.f));
        }
      }
    }
  }
  __syncthreads();

  // to_grid B: x^T col-slice, persistent regs (s_xbT region overwritten by G1)
  bf16x8 xbf[2][2];
  #pragma unroll
  for (int nt = 0; nt < 2; ++nt)
    #pragma unroll
    for (int ks = 0; ks < 2; ++ks)
      xbf[nt][ks] = ld8(&s_xbT[(wv * 32 + nt * 16 + lr) * 72 + ks * 32 + lk * 8]);

  f32x4 xo[4][2];
  #pragma unroll
  for (int mt = 0; mt < 4; ++mt)
    #pragma unroll
    for (int nt = 0; nt < 2; ++nt) xo[mt][nt] = (f32x4){0.f,0.f,0.f,0.f};

  const ushort* tgP = wbf + WS_TGP;
  const ushort* fgT = wbf + WS_FGT;

  #pragma unroll 1
  for (int ch = 0; ch < 3; ++ch) {           // 128 grid rows per iteration
    // ---- TG: Ga = tg[128,64p] @ x[64p,256]. reg-dim -> h. ----
    {
      f32x4 c[8][2];
      #pragma unroll
      for (int mt = 0; mt < 8; ++mt)
        #pragma unroll
        for (int nt = 0; nt < 2; ++nt) c[mt][nt] = (f32x4){0.f,0.f,0.f,0.f};
      #pragma unroll
      for (int ks = 0; ks < 2; ++ks) {
        #pragma unroll
        for (int hf = 0; hf < 2; ++hf) {
          bf16x8 atg[4];
          #pragma unroll
          for (int m4 = 0; m4 < 4; ++m4)
            atg[m4] = ld8(tgP + ((ch * 128 + (hf * 4 + m4) * 16 + lr) << 6) + ks * 32 + lk * 8);
          #pragma unroll
          for (int m4 = 0; m4 < 4; ++m4)
            #pragma unroll
            for (int nt = 0; nt < 2; ++nt)
              c[hf * 4 + m4][nt] = MFMA(xbf[nt][ks], atg[m4], c[hf * 4 + m4][nt]);
        }
      }
      #pragma unroll
      for (int mt = 0; mt < 8; ++mt)
        #pragma unroll
        for (int nt = 0; nt < 2; ++nt)
          *reinterpret_cast<ushort4*>(&Ga[(mt * 16 + lr) * 264 + wv * 32 + nt * 16 + lk * 4]) =
              pk4(c[mt][nt][0], c[mt][nt][1], c[mt][nt][2], c[mt][nt][3]);
    }
    __syncthreads();

    // ---- G1: Gb = silu(Ga @ g1). reg-dim -> h. ----
    {
      const ushort* gT = wbf + WS_G1T;
      f32x4 c[8][2];
      #pragma unroll
      for (int mt = 0; mt < 8; ++mt)
        #pragma unroll
        for (int nt = 0; nt < 2; ++nt) c[mt][nt] = (f32x4){0.f,0.f,0.f,0.f};
      #pragma unroll
      for (int ks = 0; ks < 8; ++ks) {
        bf16x8 bstr[2];
        #pragma unroll
        for (int nt = 0; nt < 2; ++nt)
          bstr[nt] = ld8(gT + ((wv * 32 + nt * 16 + lr) << 8) + ks * 32 + lk * 8);
        #pragma unroll
        for (int hf = 0; hf < 2; ++hf) {
          bf16x8 af[4];
          #pragma unroll
          for (int m4 = 0; m4 < 4; ++m4)
            af[m4] = ld8(&Ga[((hf * 4 + m4) * 16 + lr) * 264 + ks * 32 + lk * 8]);
          #pragma unroll
          for (int m4 = 0; m4 < 4; ++m4)
            #pragma unroll
            for (int nt = 0; nt < 2; ++nt)
              c[hf * 4 + m4][nt] = MFMA(bstr[nt], af[m4], c[hf * 4 + m4][nt]);
        }
      }
      #pragma unroll
      for (int mt = 0; mt < 8; ++mt)
        #pragma unroll
        for (int nt = 0; nt < 2; ++nt)
          *reinterpret_cast<ushort4*>(&Gb[(mt * 16 + lr) * 264 + wv * 32 + nt * 16 + lk * 4]) =
              pk4(silu_f(c[mt][nt][0]), silu_f(c[mt][nt][1]),
                  silu_f(c[mt][nt][2]), silu_f(c[mt][nt][3]));
    }
    __syncthreads();

    // ---- G2: Ga = silu(Gb @ g2). ----
    {
      const ushort* gT = wbf + WS_G1T + 65536;
      f32x4 c[8][2];
      #pragma unroll
      for (int mt = 0; mt < 8; ++mt)
        #pragma unroll
        for (int nt = 0; nt < 2; ++nt) c[mt][nt] = (f32x4){0.f,0.f,0.f,0.f};
      #pragma unroll
      for (int ks = 0; ks < 8; ++ks) {
        bf16x8 bstr[2];
        #pragma unroll
        for (int nt = 0; nt < 2; ++nt)
          bstr[nt] = ld8(gT + ((wv * 32 + nt * 16 + lr) << 8) + ks * 32 + lk * 8);
        #pragma unroll
        for (int hf = 0; hf < 2; ++hf) {
          bf16x8 af[4];
          #pragma unroll
          for (int m4 = 0; m4 < 4; ++m4)
            af[m4] = ld8(&Gb[((hf * 4 + m4) * 16 + lr) * 264 + ks * 32 + lk * 8]);
          #pragma unroll
          for (int m4 = 0; m4 < 4; ++m4)
            #pragma unroll
            for (int nt = 0; nt < 2; ++nt)
              c[hf * 4 + m4][nt] = MFMA(bstr[nt], af[m4], c[hf * 4 + m4][nt]);
        }
      }
      #pragma unroll
      for (int mt = 0; mt < 8; ++mt)
        #pragma unroll
        for (int nt = 0; nt < 2; ++nt)
          *reinterpret_cast<ushort4*>(&Ga[(mt * 16 + lr) * 264 + wv * 32 + nt * 16 + lk * 4]) =
              pk4(silu_f(c[mt][nt][0]), silu_f(c[mt][nt][1]),
                  silu_f(c[mt][nt][2]), silu_f(c[mt][nt][3]));
    }
    __syncthreads();

    // ---- G3: GT(in Gb) = (Ga @ g3)^T. reg-dim -> r. Gb's G2-reads done (pre-b3). ----
    {
      const ushort* gT = wbf + WS_G1T + 131072;
      f32x4 c[8][2];
      #pragma unroll
      for (int mt = 0; mt < 8; ++mt)
        #pragma unroll
        for (int nt = 0; nt < 2; ++nt) c[mt][nt] = (f32x4){0.f,0.f,0.f,0.f};
      #pragma unroll
      for (int ks = 0; ks < 8; ++ks) {
        bf16x8 bstr[2];
        #pragma unroll
        for (int nt = 0; nt < 2; ++nt)
          bstr[nt] = ld8(gT + ((wv * 32 + nt * 16 + lr) << 8) + ks * 32 + lk * 8);
        #pragma unroll
        for (int hf = 0; hf < 2; ++hf) {
          bf16x8 af[4];
          #pragma unroll
          for (int m4 = 0; m4 < 4; ++m4)
            af[m4] = ld8(&Ga[((hf * 4 + m4) * 16 + lr) * 264 + ks * 32 + lk * 8]);
          #pragma unroll
          for (int m4 = 0; m4 < 4; ++m4)
            #pragma unroll
            for (int nt = 0; nt < 2; ++nt)
              c[hf * 4 + m4][nt] = MFMA(af[m4], bstr[nt], c[hf * 4 + m4][nt]);
        }
      }
      #pragma unroll
      for (int mt = 0; mt < 8; ++mt)
        #pragma unroll
        for (int nt = 0; nt < 2; ++nt) {
          int h = wv * 32 + nt * 16 + lr;
          *reinterpret_cast<ushort4*>(&Gb[h * 136 + mt * 16 + lk * 4]) =
              pk4(c[mt][nt][0], c[mt][nt][1], c[mt][nt][2], c[mt][nt][3]);
        }
    }
    __syncthreads();

    // ---- FG: xo += fg[128]^T @ GT(Gb). reg-dim -> h. No trailing barrier:
    //      next TG writes Ga only; next-iter b1 orders Gb reuse by G1. ----
    {
      #pragma unroll
      for (int ks = 0; ks < 4; ++ks) {
        bf16x8 afg[4];
        #pragma unroll
        for (int mt = 0; mt < 4; ++mt)
          afg[mt] = ld8(fgT + (mt * 16 + lr) * 384 + ch * 128 + ks * 32 + lk * 8);
        bf16x8 bfr[2];
        #pragma unroll
        for (int nt = 0; nt < 2; ++nt)
          bfr[nt] = ld8(&Gb[(wv * 32 + nt * 16 + lr) * 136 + ks * 32 + lk * 8]);
        #pragma unroll
        for (int mt = 0; mt < 4; ++mt)
          #pragma unroll
          for (int nt = 0; nt < 2; ++nt) xo[mt][nt] = MFMA(bfr[nt], afg[mt], xo[mt][nt]);
      }
    }
  }

  // ---------------- epilogue: xo -> s_xo (Ga), gating row, SO3 linear 2 ----------------
  #pragma unroll
  for (int mt = 0; mt < 4; ++mt)
    #pragma unroll
    for (int nt = 0; nt < 2; ++nt)
      *reinterpret_cast<ushort4*>(&s_xo[(mt * 16 + lr) * 264 + wv * 32 + nt * 16 + lk * 4]) =
          pk4(xo[mt][nt][0], xo[mt][nt][1], xo[mt][nt][2], xo[mt][nt][3]);
  __syncthreads();
  if (tid < 256) s_xo[tid] = f2b(gat);   // row 0 <- gating
  __syncthreads();

  {
    const ushort* w2T = wbf + WS_W2T;
    float* outp = out + (size_t)blockIdx.x * 6272;
    const float4 bb2 = *reinterpret_cast<const float4*>(b2 + wv * 16 + lk * 4);
    #pragma unroll 1
    for (int l = 0; l < 7; ++l) {
      f32x4 acc = {0.f,0.f,0.f,0.f};
      const ushort* bb = w2T + (l << 15);
      const int arow = l * l + lr;                 // <= 51; rows 49..63 are zeros
      #pragma unroll
      for (int ks = 0; ks < 8; ++ks) {
        bf16x8 xf = ld8(&s_xo[arow * 264 + ks * 32 + lk * 8]);
        bf16x8 wf = ld8(bb + ((wv * 16 + lr) << 8) + ks * 32 + lk * 8);
        acc = MFMA(wf, xf, acc);                   // reg-dim -> o
      }
      if (lr < 2 * l + 1) {
        int ig = l * l + lr;
        float4 v = make_float4(acc[0], acc[1], acc[2], acc[3]);
        if (ig == 0) { v.x += bb2.x; v.y += bb2.y; v.z += bb2.z; v.w += bb2.w; }
        *reinterpret_cast<float4*>(outp + (ig << 7) + wv * 16 + lk * 4) = v;
      }
    }
  }
}

extern "C" void kernel_launch(void* const* d_in, const int* in_sizes, int n_in,
                              void* d_out, int out_size, void* d_ws, size_t ws_size,
                              hipStream_t stream) {
  const float* nf  = (const float*)d_in[0];
  const float* w1  = (const float*)d_in[1];
  const float* b1  = (const float*)d_in[2];
  const float* w2  = (const float*)d_in[3];
  const float* b2  = (const float*)d_in[4];
  const float* wsg = (const float*)d_in[5];
  const float* bs  = (const float*)d_in[6];
  const float* g1  = (const float*)d_in[7];
  const float* g2  = (const float*)d_in[8];
  const float* g3  = (const float*)d_in[9];
  const float* tg  = (const float*)d_in[10];
  const float* fg  = (const float*)d_in[11];
  ushort* wbf = (ushort*)d_ws;
  float* out = (float*)d_out;

  prep_kernel<<<(WS_TOTAL + 255) / 256, 256, 0, stream>>>(w1, w2, g1, g2, g3, tg, fg, wbf);
  ffn_main<<<1024, 512, 0, stream>>>(nf, b1, b2, wsg, bs, wbf, out);
}